// Round 5
// baseline (477.034 us; speedup 1.0000x reference)
//
#include <hip/hip_runtime.h>

// Walsh-Hadamard (n=4096) per row + affine epilogue: out = scale*(H x)/64 + shift
// v5: double-buffered async-DMA pipeline, radix 16x16x16.
//
// v4 residual: single stage buffer forced DMA issue AFTER R1 drained it ->
// loads in flight only ~60% of each iteration. v5 double-buffers the stage
// and issues row r+1's global_load_lds at the TOP of iteration r (buf parity
// alternates; the buffer being overwritten was last read in iter r-1, whose
// post-R1 barrier all waves have passed). DMA duty cycle -> ~100%;
// 3 blocks/CU x 16 KB = 48 KB/CU in flight >> ~22 KB Little's-law need.
//
// vmcnt bookkeeping (exact counting verified safe by v4 passing):
//   per wave per iter: [4 glld] ... [16 nt stores]. At top of iter r the
//   outstanding set is glld(r)x4 (oldest), store(r-1)x16, glld(r+1)x4 ->
//   WAIT vmcnt(20) drains exactly glld(r). Last iter issues no glld ->
//   WAIT vmcnt(16). Never drain to 0 inside the loop (T4).
//
// Digit order: R1 transforms i2, R2 transforms i0, R3 transforms i1 ->
// final ownership e = 256*(t>>4) + 16*k + (t&15): each store instruction
// covers 4 FULLY-WRITTEN 64B lines -> nontemporal dword stores are safe
// (v3 measured WRITE_SIZE = 262 MB = ideal with this class of pattern).
// scale/shift at e are row-invariant -> preloaded once (16+16 VGPR).
//
// work layout addr = S2*i2 + SI1*i1 + i0 (S2=277, SI1=17): all LDS phases
// <= ~3-way bank multiplicity (hand-checked mod-32 algebra); LDS pipe is
// ~10x off the critical path anyway.
// LDS: 2*16384 + 17728 = 50496 B -> 3 blocks/CU (12 waves/CU).

#define ROW 4096
#define NT 256
#define RPB 8    // rows per block; grid = 16384/8 = 2048
#define S2 277   // work stride for i2 digit (odd)
#define SI1 17   // work weight for i1 digit (odd)

__device__ __forceinline__ void wht16(float v[16]) {
#pragma unroll
  for (int h = 1; h < 16; h <<= 1) {
#pragma unroll
    for (int i = 0; i < 16; ++i) {
      if ((i & h) == 0) {
        float a = v[i], b = v[i | h];
        v[i] = a + b;
        v[i | h] = a - b;
      }
    }
  }
}

__device__ __forceinline__ void glld16(const float* g, float* l) {
  // async 16 B/lane global->LDS; LDS dest = wave-uniform base + lane*16 (HW).
  __builtin_amdgcn_global_load_lds(
      (const __attribute__((address_space(1))) void*)g,
      (__attribute__((address_space(3))) void*)l, 16, 0, 0);
}

#define WAIT_VM(N)                                      \
  asm volatile("s_waitcnt vmcnt(" #N ")" ::: "memory"); \
  __builtin_amdgcn_sched_barrier(0)
#define WAIT_LGKM                                    \
  asm volatile("s_waitcnt lgkmcnt(0)" ::: "memory"); \
  __builtin_amdgcn_sched_barrier(0)
#define BAR asm volatile("s_barrier" ::: "memory")

__global__ __launch_bounds__(NT, 3) void AdaptiveHadamardTransform_kernel(
    const float* __restrict__ x, const float* __restrict__ scale,
    const float* __restrict__ shift, float* __restrict__ out) {
  __shared__ float stage[2][ROW];   // 32768 B, linear (glld destinations)
  __shared__ float work[16 * S2];   // 17728 B, odd-weight layout

  const int t = threadIdx.x;
  const int wid = t >> 6, lane = t & 63;
  const long long row0 = (long long)blockIdx.x * RPB;

  // ---- scale/shift preload at final ownership e(k) = 256*(t>>4)+16k+(t&15).
  float sc[16], sh[16];
  {
    const int eb = 256 * (t >> 4) + (t & 15);
#pragma unroll
    for (int k = 0; k < 16; ++k) {
      sc[k] = scale[eb + 16 * k];
      sh[k] = shift[eb + 16 * k];
    }
  }

  // per-thread LDS word offsets (row-invariant)
  const int c1 = SI1 * (t >> 4) + (t & 15);       // R1 write: work[S2*k + c1]
  const int c2 = S2 * (t >> 4) + (t & 15);        // R3:       work[c2 + SI1*k]
  const int c3 = S2 * (t >> 4) + SI1 * (t & 15);  // R2:       work[c3 + k]

  // ---- prologue: stage row0 into buf0, drain, barrier.
  {
    const float* g = x + row0 * ROW;
#pragma unroll
    for (int q = 0; q < 4; ++q)
      glld16(g + (wid * 4 + q) * 256 + lane * 4, &stage[0][(wid * 4 + q) * 256]);
  }
  WAIT_VM(0);
  BAR;

  float v[16];
  const float norm = 0.015625f;  // 1/sqrt(4096)

#pragma unroll
  for (int r = 0; r < RPB; ++r) {
    const long long base = (row0 + r) * ROW;

    // ---- issue next row's DMA FIRST (into the other buffer): in flight
    // across this entire iteration. Safe: buf[(r+1)&1] was last read in
    // iter r-1's R1, sealed by its post-R1 barrier.
    if (r + 1 < RPB) {
      const float* g = x + base + ROW;
      float* dst = stage[(r + 1) & 1];
#pragma unroll
      for (int q = 0; q < 4; ++q)
        glld16(g + (wid * 4 + q) * 256 + lane * 4, dst + (wid * 4 + q) * 256);
    }

    if (r) {
      // drain exactly glld(row r); leave prev stores + new glld flying.
      if (r + 1 < RPB) {
        WAIT_VM(20);
      } else {
        WAIT_VM(16);  // last iter: no new glld issued above
      }
      BAR;  // all waves' glld(r) done; also WAR guard for work (prev R3)
    }

    // ---- R1: stage -> regs (bank = t%32, 2-way free), wht over i2 -> work.
    const float* sbuf = stage[r & 1];
#pragma unroll
    for (int k = 0; k < 16; ++k) v[k] = sbuf[t + 256 * k];
    wht16(v);
#pragma unroll
    for (int k = 0; k < 16; ++k) work[S2 * k + c1] = v[k];
    WAIT_LGKM;
    BAR;  // stage[r&1] free + work visible cross-wave

    // ---- R2: own (i2,i1) = (t>>4, t&15); vary k = i0 (contiguous reads,
    // ~2-way banks: 17 invertible mod 32). wht over i0; write back in place.
#pragma unroll
    for (int k = 0; k < 16; ++k) v[k] = work[c3 + k];
    wht16(v);
#pragma unroll
    for (int k = 0; k < 16; ++k) work[c3 + k] = v[k];
    WAIT_LGKM;
    BAR;

    // ---- R3: own (i2,i0) = (t>>4, t&15); vary k = i1 (~3-way banks).
#pragma unroll
    for (int k = 0; k < 16; ++k) v[k] = work[c2 + SI1 * k];
    wht16(v);  // transform i1

    // ---- epilogue: e(k) = 256*(t>>4) + 16k + (t&15). Each store instr
    // covers 4 fully-written 64B lines -> nt dword stores, no amplification
    // (v3-verified pattern class), and output never pollutes L3.
    float* orow = out + base + 256 * (t >> 4) + (t & 15);
#pragma unroll
    for (int k = 0; k < 16; ++k) {
      const float o = fmaf(sc[k], v[k] * norm, sh[k]);
      __builtin_nontemporal_store(o, orow + 16 * k);
    }
  }
}

extern "C" void kernel_launch(void* const* d_in, const int* in_sizes, int n_in,
                              void* d_out, int out_size, void* d_ws, size_t ws_size,
                              hipStream_t stream) {
  const float* x = (const float*)d_in[0];
  const float* scale = (const float*)d_in[1];
  const float* shift = (const float*)d_in[2];
  float* out = (float*)d_out;

  const int rows = in_sizes[0] / ROW;  // 16384, divisible by RPB
  AdaptiveHadamardTransform_kernel<<<rows / RPB, NT, 0, stream>>>(x, scale, shift, out);
}

// Round 6
// 437.175 us; speedup vs baseline: 1.0912x; 1.0912x over previous
//
#include <hip/hip_runtime.h>

// Walsh-Hadamard (n=4096) per row + affine epilogue: out = scale*(H x)/64 + shift
// v6: v1's champion structure (1 row/block, 256 thr, 8 blocks/CU, 2-way-free
//     LDS, 256B/instr nt stores) with the MIDDLE transform moved from an LDS
//     round-trip to in-register ds_swizzle butterflies. Barriers 2->1 per
//     row, LDS word ops 64->32 per thread-row.
//
// Evidence (v2-v5): every scheme that reduced blocks/CU (DMA staging,
// prefetch regs, bigger LDS) lost more to latency than it recovered;
// occupancy is the dominant lever. v6 keeps v1's residency exactly
// (17408 B LDS, <=64 VGPR via __launch_bounds__(256,8) -> 8 blocks/CU)
// and only shortens the per-row serial chain.
//
// Index algebra (row elem e = 16t + j, t=thread, j=0..15):
//   digit j  (bits 0-3 of e): wht16 in registers after 4x float4 load.
//   digit m = t&15 = lane&15 (bits 4-7): butterfly partners are lane^h,
//     h in {1,2,4,8} -- all within a 32-lane half -> ds_swizzle BitMode
//     xor patterns (0x041F/0x081F/0x101F/0x201F), one fma per step:
//     v' = (lane&h ? pv - v : v + pv) = fmaf(sgn_h, v, pv).
//   digit g = t>>4 (bits 8-11): one LDS transpose (v1's verified pad-17
//     layout: write t*17+j [2-way, free], read (16r + t>>4)*17 + (t&15)
//     [3-way, minor]), then wht16 in registers.
// Final ownership e = 256r + t -> per-instr 256 contiguous bytes: nt dword
// stores are amplification-free (v3 measured WRITE=262MB ideal; v5 showed
// 64B-granule patterns amplify 1.2x -- avoided here).

#define ROW 4096
#define STR 17  // padded LDS row stride (words)

typedef int intx1;

__device__ __forceinline__ void wht16(float v[16]) {
#pragma unroll
  for (int h = 1; h < 16; h <<= 1) {
#pragma unroll
    for (int i = 0; i < 16; ++i) {
      if ((i & h) == 0) {
        float a = v[i], b = v[i | h];
        v[i] = a + b;
        v[i | h] = a - b;
      }
    }
  }
}

// one cross-lane butterfly step over lane-bit h (h in {1,2,4,8}), all 16 vals
template <int PAT>
__device__ __forceinline__ void swz_step(float v[16], float sgn) {
#pragma unroll
  for (int j = 0; j < 16; ++j) {
    const int pi = __builtin_amdgcn_ds_swizzle(__float_as_int(v[j]), PAT);
    v[j] = fmaf(sgn, v[j], __int_as_float(pi));
  }
}

__global__ __launch_bounds__(256, 8) void AdaptiveHadamardTransform_kernel(
    const float* __restrict__ x, const float* __restrict__ scale,
    const float* __restrict__ shift, float* __restrict__ out) {
  __shared__ float lds[256 * STR];  // 17408 B -> thread-limited 8 blocks/CU

  const int t = threadIdx.x;
  const int lane = t & 63;
  const long long base = (long long)blockIdx.x * ROW;

  float v[16];

  // ---- load: thread t owns e = 16t + j, 4x float4 (16 B/lane, 1 KB/instr).
  {
    const float4* __restrict__ x4 =
        reinterpret_cast<const float4*>(x + base + 16 * t);
#pragma unroll
    for (int q = 0; q < 4; ++q) {
      const float4 f = x4[q];
      v[4 * q + 0] = f.x;
      v[4 * q + 1] = f.y;
      v[4 * q + 2] = f.z;
      v[4 * q + 3] = f.w;
    }
  }

  wht16(v);  // transform digit j (in registers)

  // ---- transform digit m = lane&15 via cross-lane butterflies (no barrier,
  // no LDS buffer traffic; 16 independent chains pipeline the swizzle lat).
  swz_step<0x041F>(v, (lane & 1) ? -1.f : 1.f);
  swz_step<0x081F>(v, (lane & 2) ? -1.f : 1.f);
  swz_step<0x101F>(v, (lane & 4) ? -1.f : 1.f);
  swz_step<0x201F>(v, (lane & 8) ? -1.f : 1.f);

  // ---- single LDS transpose for digit g = t>>4 (v1-verified layout).
#pragma unroll
  for (int j = 0; j < 16; ++j) lds[t * STR + j] = v[j];  // 2-way, free
  __syncthreads();
  {
    const int i1 = t >> 4, i0 = t & 15;
#pragma unroll
    for (int r = 0; r < 16; ++r) v[r] = lds[(r * 16 + i1) * STR + i0];  // 3-way
  }

  wht16(v);  // transform digit g (in registers)

  // ---- epilogue: e(r) = 256r + t; wave covers 256 contiguous bytes per
  // store instr -> nt dword stores, no write amplification (v3-verified).
  // scale/shift loads are row-invariant addresses -> L1-hot across blocks.
  const float norm = 0.015625f;  // 1/sqrt(4096)
#pragma unroll
  for (int r = 0; r < 16; ++r) {
    const int c = r * 256 + t;
    const float o = fmaf(scale[c], v[r] * norm, shift[c]);
    __builtin_nontemporal_store(o, out + base + c);
  }
}

extern "C" void kernel_launch(void* const* d_in, const int* in_sizes, int n_in,
                              void* d_out, int out_size, void* d_ws, size_t ws_size,
                              hipStream_t stream) {
  const float* x = (const float*)d_in[0];
  const float* scale = (const float*)d_in[1];
  const float* shift = (const float*)d_in[2];
  float* out = (float*)d_out;

  const int rows = in_sizes[0] / ROW;  // 4*4096 = 16384
  AdaptiveHadamardTransform_kernel<<<rows, 256, 0, stream>>>(x, scale, shift, out);
}